// Round 7
// baseline (42.139 us; speedup 1.0000x reference)
//
#include <hip/hip_runtime.h>

// Propagation2: out[b, k, y, x] = in[b, 0, clamp(y+dy_k), clamp(x+dx_k)]
// (one-hot 5x5 conv filters == shifted copies with replication pad 2).
//
// R7 experiment: plane-split decomposition. Each block owns one (b, k) plane
// region and writes ONE contiguous NT stream (vs 9 interleaved 2MB-apart
// streams per CU in R4/R6) to test DRAM page-locality as the residual gap
// vs the ~7 TB/s pure-write fill ceiling.
// Block order (b, k, region) + 4590-block XCD chunks => XCD i gets exactly
// batch i; its 2.09 MB input stays L2-resident across all 9 planes, so read
// HBM traffic is unchanged (~17 MB).

#define H_DIM 544
#define W_DIM 960

typedef float f4 __attribute__((ext_vector_type(4)));

// OFFSETS = [(-2,0),(0,-2),(0,0),(0,2),(2,0),(-1,-1),(1,1),(-1,1),(1,-1)]
__device__ __constant__ int DY[9] = {-2, 0, 0, 0, 2, -1, 1, -1, 1};
__device__ __constant__ int DX[9] = { 0,-2, 0, 2, 0, -1, 1,  1,-1};

__global__ __launch_bounds__(256) void Propagation2_kernel(
    const float* __restrict__ in, float* __restrict__ out, int B,
    int chunks_per_xcd)
{
    const int H = H_DIM, W = W_DIM;
    const int qpr = W >> 2;                  // 240 quads per row
    const int bpp = (H * qpr) >> 8;          // 510 blocks per plane

    int bid = blockIdx.x;
    int swz = (chunks_per_xcd > 0) ? ((bid & 7) * chunks_per_xcd + (bid >> 3))
                                   : bid;

    int b   = swz / (9 * bpp);
    int rem = swz - b * (9 * bpp);
    int k   = rem / bpp;
    int r   = rem - k * bpp;

    int pos = (r << 8) + threadIdx.x;        // quad index within plane
    int y   = pos / qpr;
    int q   = pos - y * qpr;
    int x0  = q << 2;

    int dy = DY[k], dx = DX[k];              // block-uniform (scalar) reads

    int yc = y + dy;
    yc = yc < 0 ? 0 : (yc >= H ? H - 1 : yc);
    const float* row = in + ((size_t)b * H + yc) * W;

    f4 v;
#pragma unroll
    for (int j = 0; j < 4; ++j) {
        int xc = x0 + j + dx;
        xc = xc < 0 ? 0 : (xc >= W ? W - 1 : xc);
        v[j] = row[xc];
    }

    float* op = out + (((size_t)b * 9 + k) * H + y) * W + x0;
    __builtin_nontemporal_store(v, (f4*)op);
}

extern "C" void kernel_launch(void* const* d_in, const int* in_sizes, int n_in,
                              void* d_out, int out_size, void* d_ws, size_t ws_size,
                              hipStream_t stream) {
    const float* in = (const float*)d_in[0];
    float* out = (float*)d_out;
    const int H = H_DIM, W = W_DIM;
    int B = in_sizes[0] / (H * W);
    int bpp = (H * (W >> 2)) >> 8;           // 510
    int grid = B * 9 * bpp;                  // 36720 for B=8 (divisible by 8)
    int chunks_per_xcd = (grid % 8 == 0) ? grid / 8 : 0;  // 0 => identity map
    Propagation2_kernel<<<grid, 256, 0, stream>>>(in, out, B, chunks_per_xcd);
}